// Round 1
// baseline (41416.916 us; speedup 1.0000x reference)
//
#include <hip/hip_runtime.h>

#define Bsz 128
#define Tlen 1024
#define Din 256
#define Hdim 512
#define G4 2048
#define Odim 256

#define NBG 8    // batch groups (16 rows each)
#define NCG 32   // col groups (16 h-cols each)

typedef __attribute__((ext_vector_type(8))) short short8;
typedef __attribute__((ext_vector_type(4))) float f32x4;
typedef __attribute__((ext_vector_type(4))) unsigned short ushort4_;

// flags: [(Tlen+1)][NBG] padded to 32 ints (128B) each to avoid one-cacheline hotspot
#define FIDX(t, bg) (((t) * NBG + (bg)) * 32)
#define FLAGS_BYTES ((size_t)(Tlen + 1) * NBG * 32 * sizeof(int))
#define HBUF_OFF ((size_t)1049600)                       // 16B aligned, >= FLAGS_BYTES
#define HT_OFF (HBUF_OFF + (size_t)2 * Bsz * Hdim * 2)   // after bf16 hbuf[2][128][512]

__device__ inline unsigned short f2bf(float f) {
    unsigned int u = __builtin_bit_cast(unsigned int, f);
    unsigned int lsb = (u >> 16) & 1u;
    u += 0x7fffu + lsb;  // RNE
    return (unsigned short)(u >> 16);
}
__device__ inline float bf2f(unsigned short u) {
    unsigned int v = ((unsigned int)u) << 16;
    return __builtin_bit_cast(float, v);
}
__device__ inline float sigm_f(float x) { return 1.f / (1.f + __expf(-x)); }
__device__ inline float tanh_f(float x) { return 1.f - 2.f / (__expf(2.f * x) + 1.f); }

__global__ __launch_bounds__(256, 1) void lstm_persist(
    const float* __restrict__ x, const float* __restrict__ Wih,
    const float* __restrict__ Whh, const float* __restrict__ bih,
    const float* __restrict__ bhh, unsigned short* __restrict__ hbuf,
    float* __restrict__ hT, int* __restrict__ flags) {
    __shared__ unsigned char h_lds[16 * 1024];   // [16][512] bf16, swizzled
    __shared__ unsigned char xh_lds[16 * 512];   // [16][256] bf16 hi, swizzled
    __shared__ unsigned char xl_lds[16 * 512];   // lo part
    __shared__ float gates_lds[16 * 68];         // [16 batch][64 gate-cols], pad 68

    const int tid = threadIdx.x;
    const int bid = blockIdx.x;
    const int bg = bid & 7;    // batch group -> XCD-affine (bid%8 round-robin)
    const int cg = bid >> 3;   // col group 0..31
    const int lane = tid & 63;
    const int w = tid >> 6;    // wave id == gate id (0=i,1=f,2=g,3=o)
    const int n15 = lane & 15;
    const int k8 = lane >> 4;
    const int grow = bg * 16;  // global batch row base

    // ---- one-time: load this wave's W fragments into registers ----
    const int R = w * 512 + cg * 16 + n15;  // global gate row for B-frag lane
    short8 whh[16], wihh[8], wihl[8];
    {
        const float* wr = Whh + (size_t)R * Hdim;
#pragma unroll
        for (int kc = 0; kc < 16; kc++) {
            const float* p = wr + kc * 32 + k8 * 8;
            short8 f;
#pragma unroll
            for (int e = 0; e < 8; e++) f[e] = (short)f2bf(p[e]);
            whh[kc] = f;
        }
        const float* wr2 = Wih + (size_t)R * Din;
#pragma unroll
        for (int kc = 0; kc < 8; kc++) {
            const float* p = wr2 + kc * 32 + k8 * 8;
            short8 fh, fl;
#pragma unroll
            for (int e = 0; e < 8; e++) {
                float v = p[e];
                unsigned short hi = f2bf(v);
                fh[e] = (short)hi;
                fl[e] = (short)f2bf(v - bf2f(hi));
            }
            wihh[kc] = fh;
            wihl[kc] = fl;
        }
    }

    // elementwise mapping: thread -> (batch row eb, col ej) of the 16x16 h tile
    const int eb = tid >> 4;
    const int ej = tid & 15;
    float bias4[4];
#pragma unroll
    for (int g = 0; g < 4; g++) {
        int Rg = g * 512 + cg * 16 + ej;
        bias4[g] = bih[Rg] + bhh[Rg];
    }
    float c_reg = 0.f;
    float h_last = 0.f;

    for (int t = 0; t < Tlen; ++t) {
        // prefetch x tile chunks (read-only; overlaps the flag spin)
        float4 xch[4];
#pragma unroll
        for (int i = 0; i < 4; i++) {
            int cidx = tid + i * 256;
            int row = cidx >> 6;
            int c4 = cidx & 63;
            xch[i] = *(const float4*)(x + (size_t)(grow + row) * Tlen * Din +
                                      (size_t)t * Din + c4 * 4);
        }

        if (t > 0) {
            if (tid == 0) {
                int guard = 0;
                while (__hip_atomic_load(&flags[FIDX(t, bg)], __ATOMIC_ACQUIRE,
                                         __HIP_MEMORY_SCOPE_AGENT) < NCG) {
                    if (++guard > (1 << 18)) break;  // safety: no hang on anomaly
                }
            }
            __syncthreads();
            __threadfence();  // acquire: invalidate stale L1/L2 before h reads
            const unsigned short* hsrc =
                hbuf + (size_t)(t & 1) * Bsz * Hdim + (size_t)grow * Hdim;
#pragma unroll
            for (int i = 0; i < 4; i++) {
                int cidx = tid + i * 256;
                int row = cidx >> 6;
                int c16 = cidx & 63;
                short8 v = *(const short8*)(hsrc + row * Hdim + c16 * 8);
                *(short8*)(h_lds + (((row << 10) + (c16 << 4)) ^ ((row & 7) << 4))) = v;
            }
        } else {
            short8 z = {0, 0, 0, 0, 0, 0, 0, 0};
#pragma unroll
            for (int i = 0; i < 4; i++) {
                int cidx = tid + i * 256;
                int row = cidx >> 6;
                int c16 = cidx & 63;
                *(short8*)(h_lds + (((row << 10) + (c16 << 4)) ^ ((row & 7) << 4))) = z;
            }
        }

        // stage x split hi/lo into LDS
#pragma unroll
        for (int i = 0; i < 4; i++) {
            int cidx = tid + i * 256;
            int row = cidx >> 6;
            int c4 = cidx & 63;
            float vv[4] = {xch[i].x, xch[i].y, xch[i].z, xch[i].w};
            ushort4_ vh, vl;
#pragma unroll
            for (int e = 0; e < 4; e++) {
                unsigned short hi = f2bf(vv[e]);
                vh[e] = hi;
                vl[e] = f2bf(vv[e] - bf2f(hi));
            }
            int a = ((row << 9) + (c4 << 3)) ^ ((row & 7) << 4);
            *(ushort4_*)(xh_lds + a) = vh;
            *(ushort4_*)(xl_lds + a) = vl;
        }
        __syncthreads();

        // GEMM: acc[16 batch x 16 gate-cols] for this wave's gate
        f32x4 acc0 = {0.f, 0.f, 0.f, 0.f}, acc1 = {0.f, 0.f, 0.f, 0.f};
#pragma unroll
        for (int kc = 0; kc < 16; kc++) {
            short8 a = *(const short8*)(h_lds + (((n15 << 10) + (kc << 6) + (k8 << 4)) ^
                                                ((n15 & 7) << 4)));
            if (kc & 1)
                acc1 = __builtin_amdgcn_mfma_f32_16x16x32_bf16(a, whh[kc], acc1, 0, 0, 0);
            else
                acc0 = __builtin_amdgcn_mfma_f32_16x16x32_bf16(a, whh[kc], acc0, 0, 0, 0);
        }
#pragma unroll
        for (int kc = 0; kc < 8; kc++) {
            int a = ((n15 << 9) + (kc << 6) + (k8 << 4)) ^ ((n15 & 7) << 4);
            short8 xh = *(const short8*)(xh_lds + a);
            short8 xl = *(const short8*)(xl_lds + a);
            acc0 = __builtin_amdgcn_mfma_f32_16x16x32_bf16(xh, wihh[kc], acc0, 0, 0, 0);
            acc1 = __builtin_amdgcn_mfma_f32_16x16x32_bf16(xl, wihh[kc], acc1, 0, 0, 0);
            if (kc & 1)
                acc1 = __builtin_amdgcn_mfma_f32_16x16x32_bf16(xh, wihl[kc], acc1, 0, 0, 0);
            else
                acc0 = __builtin_amdgcn_mfma_f32_16x16x32_bf16(xh, wihl[kc], acc0, 0, 0, 0);
        }

        // store gates to LDS (C layout: row=(lane>>4)*4+j, col=lane&15)
#pragma unroll
        for (int j2 = 0; j2 < 4; j2++) {
            int mm = k8 * 4 + j2;
            gates_lds[mm * 68 + w * 16 + n15] = acc0[j2] + acc1[j2];
        }
        __syncthreads();

        // elementwise LSTM cell update (one (b,j) per thread)
        {
            float pre[4];
#pragma unroll
            for (int g = 0; g < 4; g++) pre[g] = gates_lds[eb * 68 + g * 16 + ej] + bias4[g];
            float ig = sigm_f(pre[0]);
            float fg = sigm_f(pre[1]);
            float gg = tanh_f(pre[2]);
            float og = sigm_f(pre[3]);
            c_reg = fg * c_reg + ig * gg;
            h_last = og * tanh_f(c_reg);
            hbuf[(size_t)((t + 1) & 1) * Bsz * Hdim + (size_t)(grow + eb) * Hdim +
                 cg * 16 + ej] = f2bf(h_last);
        }
        __threadfence();  // release: make h stores device-visible
        __syncthreads();
        if (tid == 0) {
            __hip_atomic_fetch_add(&flags[FIDX(t + 1, bg)], 1, __ATOMIC_RELEASE,
                                   __HIP_MEMORY_SCOPE_AGENT);
        }
    }
    // final h in fp32 for the output projection
    hT[(size_t)(grow + eb) * Hdim + cg * 16 + ej] = h_last;
}

__global__ __launch_bounds__(256) void out_proj(const float* __restrict__ hT,
                                                const float* __restrict__ Wout,
                                                const float* __restrict__ bout,
                                                float* __restrict__ out) {
    __shared__ float h_s[16 * 512];
    __shared__ float w_s[64 * 69];
    const int tid = threadIdx.x;
    const int bt = blockIdx.x >> 2;  // 0..7 batch tile (16 rows)
    const int ot = blockIdx.x & 3;   // 0..3 out tile (64 cols)
#pragma unroll
    for (int i = 0; i < 8; i++) {
        int cidx = tid + i * 256;  // 2048 float4 chunks
        int row = cidx >> 7;
        int c4 = cidx & 127;
        *(float4*)(&h_s[row * 512 + c4 * 4]) =
            *(const float4*)(hT + (size_t)(bt * 16 + row) * 512 + c4 * 4);
    }
    const int o = tid & 63;
    const int bq = tid >> 6;
    float acc[4] = {0.f, 0.f, 0.f, 0.f};
    for (int kc = 0; kc < 8; kc++) {
        __syncthreads();
#pragma unroll
        for (int i = 0; i < 4; i++) {
            int cidx = tid + i * 256;  // 1024 float4 chunks
            int row = cidx >> 4;
            int c4 = cidx & 15;
            float4 v = *(const float4*)(Wout + (size_t)(ot * 64 + row) * 512 + kc * 64 +
                                        c4 * 4);
            float* dst = &w_s[row * 69 + c4 * 4];
            dst[0] = v.x;
            dst[1] = v.y;
            dst[2] = v.z;
            dst[3] = v.w;
        }
        __syncthreads();
#pragma unroll 16
        for (int k = 0; k < 64; k++) {
            float wv = w_s[o * 69 + k];
#pragma unroll
            for (int bi = 0; bi < 4; bi++)
                acc[bi] += h_s[(bq * 4 + bi) * 512 + kc * 64 + k] * wv;
        }
    }
    float bo = bout[ot * 64 + o];
#pragma unroll
    for (int bi = 0; bi < 4; bi++)
        out[(size_t)(bt * 16 + bq * 4 + bi) * 256 + ot * 64 + o] = acc[bi] + bo;
}

extern "C" void kernel_launch(void* const* d_in, const int* in_sizes, int n_in,
                              void* d_out, int out_size, void* d_ws, size_t ws_size,
                              hipStream_t stream) {
    const float* x = (const float*)d_in[0];
    const float* Wih = (const float*)d_in[1];
    const float* Whh = (const float*)d_in[2];
    const float* bih = (const float*)d_in[3];
    const float* bhh = (const float*)d_in[4];
    const float* Wout = (const float*)d_in[5];
    const float* bout = (const float*)d_in[6];
    float* out = (float*)d_out;

    char* ws = (char*)d_ws;
    int* flags = (int*)ws;
    unsigned short* hbuf = (unsigned short*)(ws + HBUF_OFF);
    float* hT = (float*)(ws + HT_OFF);

    hipMemsetAsync(flags, 0, FLAGS_BYTES, stream);
    lstm_persist<<<dim3(256), dim3(256), 0, stream>>>(x, Wih, Whh, bih, bhh, hbuf, hT,
                                                      flags);
    out_proj<<<dim3(32), dim3(256), 0, stream>>>(hT, Wout, bout, out);
}

// Round 2
// 4334.331 us; speedup vs baseline: 9.5555x; 9.5555x over previous
//
#include <hip/hip_runtime.h>

#define Bsz 128
#define Tlen 1024
#define Din 256
#define Hdim 512
#define G4 2048
#define Odim 256

#define NBG 8    // batch groups (16 rows each)
#define NCG 32   // col groups (16 h-cols each)

typedef __attribute__((ext_vector_type(8))) short short8;
typedef __attribute__((ext_vector_type(4))) float f32x4;
typedef __attribute__((ext_vector_type(4))) unsigned short ushort4_;

// flags: [(Tlen+1)][NBG] padded to 32 ints (128B) each to avoid one-cacheline hotspot
#define FIDX(t, bg) (((t) * NBG + (bg)) * 32)
#define FLAGS_BYTES ((size_t)(Tlen + 1) * NBG * 32 * sizeof(int))
#define HBUF_OFF ((size_t)1049600)                       // 16B aligned, >= FLAGS_BYTES
#define HT_OFF (HBUF_OFF + (size_t)2 * Bsz * Hdim * 2)   // after bf16 hbuf[2][128][512]

__device__ inline unsigned short f2bf(float f) {
    unsigned int u = __builtin_bit_cast(unsigned int, f);
    unsigned int lsb = (u >> 16) & 1u;
    u += 0x7fffu + lsb;  // RNE
    return (unsigned short)(u >> 16);
}
__device__ inline float bf2f(unsigned short u) {
    unsigned int v = ((unsigned int)u) << 16;
    return __builtin_bit_cast(float, v);
}
__device__ inline float sigm_f(float x) { return 1.f / (1.f + __expf(-x)); }
__device__ inline float tanh_f(float x) { return 1.f - 2.f / (__expf(2.f * x) + 1.f); }

__global__ __launch_bounds__(256, 1) void lstm_persist(
    const float* __restrict__ x, const float* __restrict__ Wih,
    const float* __restrict__ Whh, const float* __restrict__ bih,
    const float* __restrict__ bhh, unsigned short* __restrict__ hbuf,
    float* __restrict__ hT, int* __restrict__ flags) {
    __shared__ unsigned char h_lds[16 * 1024];   // [16][512] bf16, swizzled
    __shared__ unsigned char xh_lds[16 * 512];   // [16][256] bf16 hi, swizzled
    __shared__ unsigned char xl_lds[16 * 512];   // lo part
    __shared__ float gates_lds[16 * 68];         // [16 batch][64 gate-cols], pad 68

    const int tid = threadIdx.x;
    const int bid = blockIdx.x;
    const int bg = bid & 7;    // batch group -> XCD-affine (bid%8 round-robin)
    const int cg = bid >> 3;   // col group 0..31
    const int lane = tid & 63;
    const int w = tid >> 6;    // wave id == gate id (0=i,1=f,2=g,3=o)
    const int n15 = lane & 15;
    const int k8 = lane >> 4;
    const int grow = bg * 16;  // global batch row base

    // ---- one-time: load this wave's W fragments into registers ----
    const int R = w * 512 + cg * 16 + n15;  // global gate row for B-frag lane
    short8 whh[16], wihh[8], wihl[8];
    {
        const float* wr = Whh + (size_t)R * Hdim;
#pragma unroll
        for (int kc = 0; kc < 16; kc++) {
            const float* p = wr + kc * 32 + k8 * 8;
            short8 f;
#pragma unroll
            for (int e = 0; e < 8; e++) f[e] = (short)f2bf(p[e]);
            whh[kc] = f;
        }
        const float* wr2 = Wih + (size_t)R * Din;
#pragma unroll
        for (int kc = 0; kc < 8; kc++) {
            const float* p = wr2 + kc * 32 + k8 * 8;
            short8 fh, fl;
#pragma unroll
            for (int e = 0; e < 8; e++) {
                float v = p[e];
                unsigned short hi = f2bf(v);
                fh[e] = (short)hi;
                fl[e] = (short)f2bf(v - bf2f(hi));
            }
            wihh[kc] = fh;
            wihl[kc] = fl;
        }
    }

    // elementwise mapping: thread -> (batch row eb, col ej) of the 16x16 h tile
    const int eb = tid >> 4;
    const int ej = tid & 15;
    float bias4[4];
#pragma unroll
    for (int g = 0; g < 4; g++) {
        int Rg = g * 512 + cg * 16 + ej;
        bias4[g] = bih[Rg] + bhh[Rg];
    }
    float c_reg = 0.f;
    float h_last = 0.f;

    for (int t = 0; t < Tlen; ++t) {
        // ---- stage x split hi/lo into LDS (independent of h) ----
#pragma unroll
        for (int i = 0; i < 4; i++) {
            int cidx = tid + i * 256;
            int row = cidx >> 6;
            int c4 = cidx & 63;
            float4 xv = *(const float4*)(x + (size_t)(grow + row) * Tlen * Din +
                                         (size_t)t * Din + c4 * 4);
            float vv[4] = {xv.x, xv.y, xv.z, xv.w};
            ushort4_ vh, vl;
#pragma unroll
            for (int e = 0; e < 4; e++) {
                unsigned short hi = f2bf(vv[e]);
                vh[e] = hi;
                vl[e] = f2bf(vv[e] - bf2f(hi));
            }
            int a = ((row << 9) + (c4 << 3)) ^ ((row & 7) << 4);
            *(ushort4_*)(xh_lds + a) = vh;
            *(ushort4_*)(xl_lds + a) = vl;
        }
        __syncthreads();

        // ---- x-side MFMAs first (off the h critical path) ----
        f32x4 acc0 = {0.f, 0.f, 0.f, 0.f}, acc1 = {0.f, 0.f, 0.f, 0.f};
#pragma unroll
        for (int kc = 0; kc < 8; kc++) {
            int a = ((n15 << 9) + (kc << 6) + (k8 << 4)) ^ ((n15 & 7) << 4);
            short8 xh = *(const short8*)(xh_lds + a);
            short8 xl = *(const short8*)(xl_lds + a);
            acc0 = __builtin_amdgcn_mfma_f32_16x16x32_bf16(xh, wihh[kc], acc0, 0, 0, 0);
            acc1 = __builtin_amdgcn_mfma_f32_16x16x32_bf16(xl, wihh[kc], acc1, 0, 0, 0);
            if (kc & 1)
                acc1 = __builtin_amdgcn_mfma_f32_16x16x32_bf16(xh, wihl[kc], acc1, 0, 0, 0);
            else
                acc0 = __builtin_amdgcn_mfma_f32_16x16x32_bf16(xh, wihl[kc], acc0, 0, 0, 0);
        }

        // ---- wait for previous step's h, then load it (scoped atomics, no fences) ----
        if (t > 0) {
            if (tid == 0) {
                int v = __hip_atomic_load(&flags[FIDX(t, bg)], __ATOMIC_RELAXED,
                                          __HIP_MEMORY_SCOPE_AGENT);
                int guard = 0;
                while (v < NCG && ++guard < (1 << 20)) {
                    __builtin_amdgcn_s_sleep(1);
                    v = __hip_atomic_load(&flags[FIDX(t, bg)], __ATOMIC_RELAXED,
                                          __HIP_MEMORY_SCOPE_AGENT);
                }
            }
            __syncthreads();
            unsigned short* hsrc =
                hbuf + (size_t)(t & 1) * Bsz * Hdim + (size_t)grow * Hdim;
#pragma unroll
            for (int i = 0; i < 8; i++) {
                int cidx = tid + i * 256;  // 2048 chunks of 8B
                int row = cidx >> 7;
                int c8 = cidx & 127;
                unsigned long long v = __hip_atomic_load(
                    (unsigned long long*)(hsrc + row * Hdim + c8 * 4), __ATOMIC_RELAXED,
                    __HIP_MEMORY_SCOPE_AGENT);
                *(unsigned long long*)(h_lds +
                                       (((row << 10) + (c8 << 3)) ^ ((row & 7) << 4))) = v;
            }
        } else {
#pragma unroll
            for (int i = 0; i < 8; i++) {
                int cidx = tid + i * 256;
                int row = cidx >> 7;
                int c8 = cidx & 127;
                *(unsigned long long*)(h_lds +
                                       (((row << 10) + (c8 << 3)) ^ ((row & 7) << 4))) =
                    0ULL;
            }
        }
        __syncthreads();

        // ---- h-side MFMAs ----
#pragma unroll
        for (int kc = 0; kc < 16; kc++) {
            short8 a = *(const short8*)(h_lds + (((n15 << 10) + (kc << 6) + (k8 << 4)) ^
                                                ((n15 & 7) << 4)));
            if (kc & 1)
                acc1 = __builtin_amdgcn_mfma_f32_16x16x32_bf16(a, whh[kc], acc1, 0, 0, 0);
            else
                acc0 = __builtin_amdgcn_mfma_f32_16x16x32_bf16(a, whh[kc], acc0, 0, 0, 0);
        }

        // store gates to LDS (C layout: row=(lane>>4)*4+j, col=lane&15)
#pragma unroll
        for (int j2 = 0; j2 < 4; j2++) {
            int mm = k8 * 4 + j2;
            gates_lds[mm * 68 + w * 16 + n15] = acc0[j2] + acc1[j2];
        }
        __syncthreads();

        // ---- elementwise LSTM cell update (one (b,j) per thread) ----
        {
            float pre[4];
#pragma unroll
            for (int g = 0; g < 4; g++) pre[g] = gates_lds[eb * 68 + g * 16 + ej] + bias4[g];
            float ig = sigm_f(pre[0]);
            float fg = sigm_f(pre[1]);
            float gg = tanh_f(pre[2]);
            float og = sigm_f(pre[3]);
            c_reg = fg * c_reg + ig * gg;
            h_last = og * tanh_f(c_reg);
            // pack 2 bf16 (ej even | ej odd) and store as scoped u32 atomic
            unsigned int hb = f2bf(h_last);
            unsigned int nb = (unsigned int)__shfl_xor((int)hb, 1, 64);
            if ((tid & 1) == 0) {
                size_t idx = (size_t)((t + 1) & 1) * Bsz * Hdim +
                             (size_t)(grow + eb) * Hdim + cg * 16 + ej;
                __hip_atomic_store((unsigned int*)(hbuf + idx), hb | (nb << 16),
                                   __ATOMIC_RELAXED, __HIP_MEMORY_SCOPE_AGENT);
            }
        }
        __syncthreads();  // compiler drains vmcnt before s_barrier -> h stores visible
        if (tid == 0) {
            __hip_atomic_fetch_add(&flags[FIDX(t + 1, bg)], 1, __ATOMIC_RELAXED,
                                   __HIP_MEMORY_SCOPE_AGENT);
        }
    }
    // final h in fp32 for the output projection
    hT[(size_t)(grow + eb) * Hdim + cg * 16 + ej] = h_last;
}

__global__ __launch_bounds__(256) void out_proj(const float* __restrict__ hT,
                                                const float* __restrict__ Wout,
                                                const float* __restrict__ bout,
                                                float* __restrict__ out) {
    __shared__ float h_s[16 * 512];
    __shared__ float w_s[64 * 69];
    const int tid = threadIdx.x;
    const int bt = blockIdx.x >> 2;  // 0..7 batch tile (16 rows)
    const int ot = blockIdx.x & 3;   // 0..3 out tile (64 cols)
#pragma unroll
    for (int i = 0; i < 8; i++) {
        int cidx = tid + i * 256;  // 2048 float4 chunks
        int row = cidx >> 7;
        int c4 = cidx & 127;
        *(float4*)(&h_s[row * 512 + c4 * 4]) =
            *(const float4*)(hT + (size_t)(bt * 16 + row) * 512 + c4 * 4);
    }
    const int o = tid & 63;
    const int bq = tid >> 6;
    float acc[4] = {0.f, 0.f, 0.f, 0.f};
    for (int kc = 0; kc < 8; kc++) {
        __syncthreads();
#pragma unroll
        for (int i = 0; i < 4; i++) {
            int cidx = tid + i * 256;  // 1024 float4 chunks
            int row = cidx >> 4;
            int c4 = cidx & 15;
            float4 v = *(const float4*)(Wout + (size_t)(ot * 64 + row) * 512 + kc * 64 +
                                        c4 * 4);
            float* dst = &w_s[row * 69 + c4 * 4];
            dst[0] = v.x;
            dst[1] = v.y;
            dst[2] = v.z;
            dst[3] = v.w;
        }
        __syncthreads();
#pragma unroll 16
        for (int k = 0; k < 64; k++) {
            float wv = w_s[o * 69 + k];
#pragma unroll
            for (int bi = 0; bi < 4; bi++)
                acc[bi] += h_s[(bq * 4 + bi) * 512 + kc * 64 + k] * wv;
        }
    }
    float bo = bout[ot * 64 + o];
#pragma unroll
    for (int bi = 0; bi < 4; bi++)
        out[(size_t)(bt * 16 + bq * 4 + bi) * 256 + ot * 64 + o] = acc[bi] + bo;
}

extern "C" void kernel_launch(void* const* d_in, const int* in_sizes, int n_in,
                              void* d_out, int out_size, void* d_ws, size_t ws_size,
                              hipStream_t stream) {
    const float* x = (const float*)d_in[0];
    const float* Wih = (const float*)d_in[1];
    const float* Whh = (const float*)d_in[2];
    const float* bih = (const float*)d_in[3];
    const float* bhh = (const float*)d_in[4];
    const float* Wout = (const float*)d_in[5];
    const float* bout = (const float*)d_in[6];
    float* out = (float*)d_out;

    char* ws = (char*)d_ws;
    int* flags = (int*)ws;
    unsigned short* hbuf = (unsigned short*)(ws + HBUF_OFF);
    float* hT = (float*)(ws + HT_OFF);

    hipMemsetAsync(flags, 0, FLAGS_BYTES, stream);
    lstm_persist<<<dim3(256), dim3(256), 0, stream>>>(x, Wih, Whh, bih, bhh, hbuf, hT,
                                                      flags);
    out_proj<<<dim3(32), dim3(256), 0, stream>>>(hT, Wout, bout, out);
}

// Round 4
// 4049.007 us; speedup vs baseline: 10.2289x; 1.0705x over previous
//
#include <hip/hip_runtime.h>

#define Bsz 128
#define Tlen 1024
#define Din 256
#define Hdim 512

#define NBG 8    // batch groups (16 rows each)
#define NCG 32   // col groups (16 h-cols each)

typedef __attribute__((ext_vector_type(8))) short short8;
typedef __attribute__((ext_vector_type(4))) float f32x4;
typedef __attribute__((ext_vector_type(4))) unsigned short ushort4_;
typedef __attribute__((ext_vector_type(4))) unsigned int uint4v;

// flags: [(Tlen+1)][NBG] rows of 128 bytes; byte per (cg,wave) producer slot
#define FIDXB(t, bg) (((size_t)(t) * NBG + (bg)) * 128)
#define FLAGS_BYTES ((size_t)(Tlen + 1) * NBG * 128)    // 1,049,600
#define HBUF_OFF ((size_t)1049600)
#define HT_OFF (HBUF_OFF + (size_t)2 * Bsz * Hdim * 2)  // 1,311,744

__device__ inline unsigned short f2bf(float f) {
    unsigned int u = __builtin_bit_cast(unsigned int, f);
    unsigned int lsb = (u >> 16) & 1u;
    u += 0x7fffu + lsb;  // RNE
    return (unsigned short)(u >> 16);
}
__device__ inline float bf2f(unsigned short u) {
    unsigned int v = ((unsigned int)u) << 16;
    return __builtin_bit_cast(float, v);
}
__device__ inline float sigm_f(float x) { return 1.f / (1.f + __expf(-x)); }
__device__ inline float tanh_f(float x) { return 1.f - 2.f / (__expf(2.f * x) + 1.f); }

__device__ __forceinline__ void conv_x_to_lds(const float4* xv, int tid,
                                              unsigned char* xh, unsigned char* xl) {
#pragma unroll
    for (int i = 0; i < 4; i++) {
        int cidx = tid + i * 256;
        int row = cidx >> 6;
        int c4 = cidx & 63;
        float vv[4] = {xv[i].x, xv[i].y, xv[i].z, xv[i].w};
        ushort4_ vh, vl;
#pragma unroll
        for (int e = 0; e < 4; e++) {
            unsigned short hi = f2bf(vv[e]);
            vh[e] = hi;
            vl[e] = f2bf(vv[e] - bf2f(hi));
        }
        int a = ((row << 9) + (c4 << 3)) ^ ((row & 7) << 4);
        *(ushort4_*)(xh + a) = vh;
        *(ushort4_*)(xl + a) = vl;
    }
}

__global__ __launch_bounds__(256, 1) void lstm_persist(
    const float* __restrict__ x, const float* __restrict__ Wih,
    const float* __restrict__ Whh, const float* __restrict__ bih,
    const float* __restrict__ bhh, unsigned short* __restrict__ hbuf,
    float* __restrict__ hT, unsigned char* __restrict__ flags) {
    __shared__ unsigned char h_lds[16 * 1024];      // [16][512] bf16, swizzled
    __shared__ unsigned char xh_lds[2 * 8192];      // dbuf [16][256] bf16 hi, swizzled
    __shared__ unsigned char xl_lds[2 * 8192];      // dbuf lo
    __shared__ float gates_w[4][16 * 17];           // per-wave [16 batch][16 gcol] pad17

    const int tid = threadIdx.x;
    const int bid = blockIdx.x;
    const int bg = bid & 7;
    const int cg = bid >> 3;
    const int lane = tid & 63;
    const int w = tid >> 6;
    const int n15 = lane & 15;
    const int k8 = lane >> 4;
    const int grow = bg * 16;
    // wave owns all 4 gates for 4 h-cols: lane -> (batch myb, col mycol)
    const int gc = n15 & 3;               // col sub-index 0..3
    const int gsel = n15 >> 2;            // batch sub-index 0..3
    const int myb = k8 * 4 + gsel;        // owned batch row 0..15
    const int mycol = cg * 16 + w * 4 + gc;  // owned h column

    // ---- one-time: weight fragments. B-frag col n15 -> gate-row R ----
    const int R = (n15 >> 2) * Hdim + mycol;  // gate (n15>>2), col mycol
    short8 whh[16], wihh[8], wihl[8];
    {
        const float* wr = Whh + (size_t)R * Hdim;
#pragma unroll
        for (int kc = 0; kc < 16; kc++) {
            const float* p = wr + kc * 32 + k8 * 8;
            short8 f;
#pragma unroll
            for (int e = 0; e < 8; e++) f[e] = (short)f2bf(p[e]);
            whh[kc] = f;
        }
        const float* wr2 = Wih + (size_t)R * Din;
#pragma unroll
        for (int kc = 0; kc < 8; kc++) {
            const float* p = wr2 + kc * 32 + k8 * 8;
            short8 fh, fl;
#pragma unroll
            for (int e = 0; e < 8; e++) {
                float v = p[e];
                unsigned short hi = f2bf(v);
                fh[e] = (short)hi;
                fl[e] = (short)f2bf(v - bf2f(hi));
            }
            wihh[kc] = fh;
            wihl[kc] = fl;
        }
    }
    float bias4[4];
#pragma unroll
    for (int g = 0; g < 4; g++) bias4[g] = bih[g * Hdim + mycol] + bhh[g * Hdim + mycol];

    // ---- prologue: stage x[0] -> buf0; prefetch x[1] -> regs ----
    float4 xr[4];
    {
        const float* xb = x + (size_t)grow * (Tlen * Din);
#pragma unroll
        for (int i = 0; i < 4; i++) {
            int cidx = tid + i * 256;
            int row = cidx >> 6;
            int c4 = cidx & 63;
            xr[i] = *(const float4*)(xb + (size_t)row * (Tlen * Din) + c4 * 4);
        }
        conv_x_to_lds(xr, tid, xh_lds, xl_lds);
#pragma unroll
        for (int i = 0; i < 4; i++) {
            int cidx = tid + i * 256;
            int row = cidx >> 6;
            int c4 = cidx & 63;
            xr[i] = *(const float4*)(xb + (size_t)row * (Tlen * Din) + Din + c4 * 4);
        }
    }
    __syncthreads();

    float c_reg = 0.f, h_last = 0.f;

    for (int t = 0; t < Tlen; ++t) {
        // (1) convert xr (= x[t+1], loaded last tail) into buf[(t+1)&1]
        if (t + 1 < Tlen)
            conv_x_to_lds(xr, tid, xh_lds + ((t + 1) & 1) * 8192,
                          xl_lds + ((t + 1) & 1) * 8192);

        // (2) poll producers of h(t), then issue batched h loads
        uint4v r0, r1, r2, r3;
        if (t > 0) {
            const unsigned int* frow =
                (const unsigned int*)(flags + FIDXB(t, bg)) + (lane & 31);
            unsigned int f;
            int gg_ = 0;
            do {
                f = __hip_atomic_load(frow, __ATOMIC_RELAXED, __HIP_MEMORY_SCOPE_AGENT);
            } while (!__all(f == 0x01010101u) && ++gg_ < (1 << 17));
            const unsigned short* hsrc =
                hbuf + (size_t)(t & 1) * (Bsz * Hdim) + (size_t)grow * Hdim;
            const void* p0 = (const void*)(hsrc + ((tid) >> 6) * Hdim + ((tid)&63) * 8);
            const void* p1 =
                (const void*)(hsrc + ((tid + 256) >> 6) * Hdim + ((tid + 256) & 63) * 8);
            const void* p2 =
                (const void*)(hsrc + ((tid + 512) >> 6) * Hdim + ((tid + 512) & 63) * 8);
            const void* p3 =
                (const void*)(hsrc + ((tid + 768) >> 6) * Hdim + ((tid + 768) & 63) * 8);
            asm volatile(
                "global_load_dwordx4 %0, %4, off sc0 sc1\n\t"
                "global_load_dwordx4 %1, %5, off sc0 sc1\n\t"
                "global_load_dwordx4 %2, %6, off sc0 sc1\n\t"
                "global_load_dwordx4 %3, %7, off sc0 sc1"
                : "=&v"(r0), "=&v"(r1), "=&v"(r2), "=&v"(r3)
                : "v"(p0), "v"(p1), "v"(p2), "v"(p3)
                : "memory");
        }

        // (3) x-side MFMAs on buf[t&1] (overlaps in-flight h loads)
        unsigned char* xh = xh_lds + (t & 1) * 8192;
        unsigned char* xl = xl_lds + (t & 1) * 8192;
        f32x4 acc0 = {0.f, 0.f, 0.f, 0.f}, acc1 = {0.f, 0.f, 0.f, 0.f};
#pragma unroll
        for (int kc = 0; kc < 8; kc++) {
            int a = ((n15 << 9) + (kc << 6) + (k8 << 4)) ^ ((n15 & 7) << 4);
            short8 xhv = *(const short8*)(xh + a);
            short8 xlv = *(const short8*)(xl + a);
            acc0 = __builtin_amdgcn_mfma_f32_16x16x32_bf16(xhv, wihh[kc], acc0, 0, 0, 0);
            acc1 = __builtin_amdgcn_mfma_f32_16x16x32_bf16(xlv, wihh[kc], acc1, 0, 0, 0);
            if (kc & 1)
                acc1 = __builtin_amdgcn_mfma_f32_16x16x32_bf16(xhv, wihl[kc], acc1, 0, 0, 0);
            else
                acc0 = __builtin_amdgcn_mfma_f32_16x16x32_bf16(xhv, wihl[kc], acc0, 0, 0, 0);
        }

        // (4) wait h loads (only h loads outstanding here), fill h_lds
        if (t > 0) {
            asm volatile("s_waitcnt vmcnt(0)" ::: "memory");
#pragma unroll
            for (int i = 0; i < 4; i++) {
                int cidx = tid + i * 256;
                int row = cidx >> 6;
                int c16 = cidx & 63;
                int a = ((row << 10) + (c16 << 4)) ^ ((row & 7) << 4);
                *(uint4v*)(h_lds + a) = (i == 0 ? r0 : i == 1 ? r1 : i == 2 ? r2 : r3);
            }
        } else {
            uint4v z = {0u, 0u, 0u, 0u};
#pragma unroll
            for (int i = 0; i < 4; i++) {
                int cidx = tid + i * 256;
                int row = cidx >> 6;
                int c16 = cidx & 63;
                int a = ((row << 10) + (c16 << 4)) ^ ((row & 7) << 4);
                *(uint4v*)(h_lds + a) = z;
            }
        }
        __syncthreads();  // A: h_lds ready

        // (5) h-side MFMAs
#pragma unroll
        for (int kc = 0; kc < 16; kc++) {
            short8 a = *(const short8*)(h_lds + (((n15 << 10) + (kc << 6) + (k8 << 4)) ^
                                                ((n15 & 7) << 4)));
            if (kc & 1)
                acc1 = __builtin_amdgcn_mfma_f32_16x16x32_bf16(a, whh[kc], acc1, 0, 0, 0);
            else
                acc0 = __builtin_amdgcn_mfma_f32_16x16x32_bf16(a, whh[kc], acc0, 0, 0, 0);
        }

        // (6) gates to wave-PRIVATE LDS tile (no cross-wave barrier needed)
        float* gt = gates_w[w];
#pragma unroll
        for (int j2 = 0; j2 < 4; j2++) gt[(k8 * 4 + j2) * 17 + n15] = acc0[j2] + acc1[j2];

        // (7) elementwise LSTM cell update for (myb, mycol); intra-wave lgkmcnt only
        {
            float pre[4];
#pragma unroll
            for (int g = 0; g < 4; g++) pre[g] = gt[myb * 17 + g * 4 + gc] + bias4[g];
            float ig = sigm_f(pre[0]);
            float fg = sigm_f(pre[1]);
            float gg = tanh_f(pre[2]);
            float og = sigm_f(pre[3]);
            c_reg = fg * c_reg + ig * gg;
            h_last = og * tanh_f(c_reg);
            unsigned int hb = f2bf(h_last);
            unsigned int nb = (unsigned int)__shfl_xor((int)hb, 1, 64);
            if ((lane & 1) == 0) {  // mycol even: pack (mycol, mycol+1)
                size_t idx = (size_t)((t + 1) & 1) * (Bsz * Hdim) +
                             (size_t)(grow + myb) * Hdim + mycol;
                __hip_atomic_store((unsigned int*)(hbuf + idx), hb | (nb << 16),
                                   __ATOMIC_RELAXED, __HIP_MEMORY_SCOPE_AGENT);
            }
        }

        // (8) issue x[t+2] prefetch AFTER the h stores (counted drain keeps it in flight)
        const bool pf2 = (t + 2 < Tlen);
        __builtin_amdgcn_sched_barrier(0);
        if (pf2) {
            const float* xb = x + (size_t)grow * (Tlen * Din) + (size_t)(t + 2) * Din;
#pragma unroll
            for (int i = 0; i < 4; i++) {
                int cidx = tid + i * 256;
                int row = cidx >> 6;
                int c4 = cidx & 63;
                xr[i] = *(const float4*)(xb + (size_t)row * (Tlen * Din) + c4 * 4);
            }
        }
        __builtin_amdgcn_sched_barrier(0);
        // (9) drain h stores (leave the 4 x loads in flight), publish flag byte
        if (pf2)
            asm volatile("s_waitcnt vmcnt(4)" ::: "memory");
        else
            asm volatile("s_waitcnt vmcnt(0)" ::: "memory");
        if (lane == 0)
            __hip_atomic_store(flags + FIDXB(t + 1, bg) + (cg * 4 + w),
                               (unsigned char)1, __ATOMIC_RELAXED,
                               __HIP_MEMORY_SCOPE_AGENT);
        __syncthreads();  // C: LDS WAR hazards cleared for next step
    }

    hT[(size_t)(grow + myb) * Hdim + mycol] = h_last;
}

__global__ __launch_bounds__(256) void out_proj(const float* __restrict__ hT,
                                                const float* __restrict__ Wout,
                                                const float* __restrict__ bout,
                                                float* __restrict__ out) {
    __shared__ float h_s[16 * 512];
    __shared__ float w_s[64 * 69];
    const int tid = threadIdx.x;
    const int bt = blockIdx.x >> 2;
    const int ot = blockIdx.x & 3;
#pragma unroll
    for (int i = 0; i < 8; i++) {
        int cidx = tid + i * 256;
        int row = cidx >> 7;
        int c4 = cidx & 127;
        *(float4*)(&h_s[row * 512 + c4 * 4]) =
            *(const float4*)(hT + (size_t)(bt * 16 + row) * 512 + c4 * 4);
    }
    const int o = tid & 63;
    const int bq = tid >> 6;
    float acc[4] = {0.f, 0.f, 0.f, 0.f};
    for (int kc = 0; kc < 8; kc++) {
        __syncthreads();
#pragma unroll
        for (int i = 0; i < 4; i++) {
            int cidx = tid + i * 256;
            int row = cidx >> 4;
            int c4 = cidx & 15;
            float4 v = *(const float4*)(Wout + (size_t)(ot * 64 + row) * 512 + kc * 64 +
                                        c4 * 4);
            float* dst = &w_s[row * 69 + c4 * 4];
            dst[0] = v.x;
            dst[1] = v.y;
            dst[2] = v.z;
            dst[3] = v.w;
        }
        __syncthreads();
#pragma unroll 16
        for (int k = 0; k < 64; k++) {
            float wv = w_s[o * 69 + k];
#pragma unroll
            for (int bi = 0; bi < 4; bi++)
                acc[bi] += h_s[(bq * 4 + bi) * 512 + kc * 64 + k] * wv;
        }
    }
    float bo = bout[ot * 64 + o];
#pragma unroll
    for (int bi = 0; bi < 4; bi++)
        out[(size_t)(bt * 16 + bq * 4 + bi) * 256 + ot * 64 + o] = acc[bi] + bo;
}

extern "C" void kernel_launch(void* const* d_in, const int* in_sizes, int n_in,
                              void* d_out, int out_size, void* d_ws, size_t ws_size,
                              hipStream_t stream) {
    const float* x = (const float*)d_in[0];
    const float* Wih = (const float*)d_in[1];
    const float* Whh = (const float*)d_in[2];
    const float* bih = (const float*)d_in[3];
    const float* bhh = (const float*)d_in[4];
    const float* Wout = (const float*)d_in[5];
    const float* bout = (const float*)d_in[6];
    float* out = (float*)d_out;

    char* ws = (char*)d_ws;
    unsigned char* flags = (unsigned char*)ws;
    unsigned short* hbuf = (unsigned short*)(ws + HBUF_OFF);
    float* hT = (float*)(ws + HT_OFF);

    hipMemsetAsync(flags, 0, FLAGS_BYTES, stream);
    lstm_persist<<<dim3(256), dim3(256), 0, stream>>>(x, Wih, Whh, bih, bhh, hbuf, hT,
                                                      flags);
    out_proj<<<dim3(32), dim3(256), 0, stream>>>(hT, Wout, bout, out);
}